// Round 2
// baseline (71.209 us; speedup 1.0000x reference)
//
#include <hip/hip_runtime.h>
#include <hip/hip_bf16.h>
#include <math.h>

typedef float f32x4 __attribute__((ext_vector_type(4)));
typedef __bf16 bf16x8 __attribute__((ext_vector_type(8)));
typedef unsigned short ushort4_t __attribute__((ext_vector_type(4)));

#define B_ 8
#define S_ 2048
#define D_ 1024
#define H_ 64
#define M_ (B_*S_)   // 16384

static __device__ __forceinline__ unsigned short f2bf(float f) {
    __bf16 h = (__bf16)f;
    return __builtin_bit_cast(unsigned short, h);
}

static __device__ __forceinline__ void gload16(const void* g, void* l) {
    __builtin_amdgcn_global_load_lds(
        (__attribute__((address_space(1))) void*)(void*)g,
        (__attribute__((address_space(3))) void*)l, 16, 0, 0);
}

// Stage a contiguous 8KB global region into LDS with inverse-swizzled SOURCE so
// that reads with byte ^ ((row&7)<<4) (row = byte>>7, 128B rows) see logical data.
static __device__ __forceinline__ void stage_contig(const char* gsrc, char* dst, int w, int lane) {
#pragma unroll
    for (int i = 0; i < 2; ++i) {
        int ch = w * 128 + i * 64 + lane;
        int p = ch * 16;
        int so = p ^ (((p >> 7) & 7) << 4);
        gload16(gsrc + so, dst + (w * 128 + i * 64) * 16);
    }
}

// Stage a [64 rows][128B] tile whose global rows are strided (vT: 4096B stride).
static __device__ __forceinline__ void stage_v(const unsigned short* Vb, int k0, char* dst, int w, int lane) {
#pragma unroll
    for (int i = 0; i < 2; ++i) {
        int ch = w * 128 + i * 64 + lane;
        int p = ch * 16;
        int rr = p >> 7;
        int off = (p ^ ((rr & 7) << 4)) & 127;
        const char* gsrc = (const char*)(Vb + (size_t)rr * 2048 + k0) + off;
        gload16(gsrc, dst + (w * 128 + i * 64) * 16);
    }
}

// Stage Wt tile: 192 rows x 128B, global row stride 2048B. 1536 chunks, 6 per wave-lane.
static __device__ __forceinline__ void stage_wt(const unsigned short* Wt, int kt, char* dst, int w, int lane) {
#pragma unroll
    for (int i = 0; i < 6; ++i) {
        int ch = w * 384 + i * 64 + lane;
        int p = ch * 16;
        int rr = p >> 7;
        int off = (p ^ ((rr & 7) << 4)) & 127;
        const char* gsrc = (const char*)Wt + (size_t)rr * 2048 + kt * 128 + off;
        gload16(gsrc, dst + (w * 384 + i * 64) * 16);
    }
}

// ---------------- Kernel 0: W [1024][64] f32 -> Wt [3][64][1024] bf16 ----------------
__global__ __launch_bounds__(256) void prep_w_kernel(const float* __restrict__ Wq,
                                                     const float* __restrict__ Wk,
                                                     const float* __restrict__ Wv,
                                                     unsigned short* __restrict__ Wt) {
    __shared__ float tile[64][65];
    int which = blockIdx.y;
    const float* W = (which == 0) ? Wq : ((which == 1) ? Wk : Wv);
    int k0 = blockIdx.x * 64;
    int t = threadIdx.x;
    int r = t >> 2, c0 = (t & 3) * 16;
#pragma unroll
    for (int j = 0; j < 16; ++j) tile[r][c0 + j] = W[(size_t)(k0 + r) * 64 + c0 + j];
    __syncthreads();
    unsigned short* dst = Wt + (size_t)(which * 64 + r) * 1024 + k0 + c0;
#pragma unroll
    for (int j = 0; j < 16; ++j) dst[j] = f2bf(tile[c0 + j][r]);
}

// ---------------- Kernel 1: qkv projection ----------------
// out: qw,kw natural [M][64] bf16 ; vw transposed [B][64][2048] bf16
__global__ __launch_bounds__(256) void qkv_kernel(const float* __restrict__ x,
                                                  const unsigned short* __restrict__ Wt,
                                                  unsigned short* __restrict__ qw,
                                                  unsigned short* __restrict__ kw,
                                                  unsigned short* __restrict__ vw) {
    __shared__ __align__(16) char lds[8192 + 2 * 24576];
    char* xs = lds;
    int t = threadIdx.x, lane = t & 63, w = t >> 6, g = lane >> 4, qi = lane & 15;
    int m0 = blockIdx.x * 64;
    int row = t >> 2, kc = (t & 3) * 16;
    const float* xrow = x + (size_t)(m0 + row) * 1024 + kc;

    f32x4 acc[12];
#pragma unroll
    for (int n = 0; n < 12; ++n) acc[n] = (f32x4){0.f, 0.f, 0.f, 0.f};

    // prologue: x tile0 -> regs, Wt tile0 -> LDS buf0
    float4 xr0 = *(const float4*)(xrow + 0);
    float4 xr1 = *(const float4*)(xrow + 4);
    float4 xr2 = *(const float4*)(xrow + 8);
    float4 xr3 = *(const float4*)(xrow + 12);
    stage_wt(Wt, 0, lds + 8192, w, lane);

    int cur = 0;
    for (int kt = 0; kt < 16; ++kt) {
        // write xs from regs (swizzled both sides)
        bf16x8 lo, hi;
        lo[0] = (__bf16)xr0.x; lo[1] = (__bf16)xr0.y; lo[2] = (__bf16)xr0.z; lo[3] = (__bf16)xr0.w;
        lo[4] = (__bf16)xr1.x; lo[5] = (__bf16)xr1.y; lo[6] = (__bf16)xr1.z; lo[7] = (__bf16)xr1.w;
        hi[0] = (__bf16)xr2.x; hi[1] = (__bf16)xr2.y; hi[2] = (__bf16)xr2.z; hi[3] = (__bf16)xr2.w;
        hi[4] = (__bf16)xr3.x; hi[5] = (__bf16)xr3.y; hi[6] = (__bf16)xr3.z; hi[7] = (__bf16)xr3.w;
        int b0 = row * 128 + kc * 2;
        int sw = (row & 7) << 4;
        *(bf16x8*)(xs + (b0 ^ sw)) = lo;
        *(bf16x8*)(xs + ((b0 + 16) ^ sw)) = hi;
        __syncthreads();  // xs visible; Wt(kt) vmcnt-drained

        if (kt < 15) {
            const float* nsrc = xrow + (kt + 1) * 64;
            xr0 = *(const float4*)(nsrc + 0);
            xr1 = *(const float4*)(nsrc + 4);
            xr2 = *(const float4*)(nsrc + 8);
            xr3 = *(const float4*)(nsrc + 12);
            stage_wt(Wt, kt + 1, lds + 8192 + (cur ^ 1) * 24576, w, lane);
        }
        const char* wsb = lds + 8192 + cur * 24576;

        int arow = w * 16 + qi;
        int swa = (arow & 7) << 4;
#pragma unroll
        for (int ks = 0; ks < 2; ++ks) {
            bf16x8 a = *(const bf16x8*)(xs + ((arow * 128 + ks * 64 + g * 16) ^ swa));
#pragma unroll
            for (int n = 0; n < 12; ++n) {
                int brow = n * 16 + qi;
                bf16x8 bb = *(const bf16x8*)(wsb + ((brow * 128 + ks * 64 + g * 16) ^ ((brow & 7) << 4)));
                acc[n] = __builtin_amdgcn_mfma_f32_16x16x32_bf16(a, bb, acc[n], 0, 0, 0);
            }
        }
        __syncthreads();
        cur ^= 1;
    }

    // epilogue: D layout col=lane&15, row=(lane>>4)*4+reg
    int bq = m0 >> 11;             // batch
    int sl = (m0 & 2047) + w * 16 + g * 4;  // s within batch
#pragma unroll
    for (int n = 0; n < 12; ++n) {
        int col = (n & 3) * 16 + qi;
        int which = n >> 2;
        if (which == 0) {
#pragma unroll
            for (int r = 0; r < 4; ++r)
                qw[(size_t)(m0 + w * 16 + g * 4 + r) * 64 + col] = f2bf(acc[n][r]);
        } else if (which == 1) {
#pragma unroll
            for (int r = 0; r < 4; ++r)
                kw[(size_t)(m0 + w * 16 + g * 4 + r) * 64 + col] = f2bf(acc[n][r]);
        } else {
            ushort4_t pv;
            pv[0] = f2bf(acc[n][0]); pv[1] = f2bf(acc[n][1]);
            pv[2] = f2bf(acc[n][2]); pv[3] = f2bf(acc[n][3]);
            *(ushort4_t*)(vw + (size_t)bq * 64 * 2048 + (size_t)col * 2048 + sl) = pv;
        }
    }
}

// ---------------- Kernel 2: flash attention ----------------
__global__ __launch_bounds__(256) void attn_kernel(const unsigned short* __restrict__ qw,
                                                   const unsigned short* __restrict__ kw,
                                                   const unsigned short* __restrict__ vw,
                                                   float* __restrict__ out) {
    __shared__ __align__(16) char lds[49152];
    // byte-offset layout (no LDS pointer arrays — addrspacecast static-init issue):
    //   K double-buffer: [0, 8192) and [8192, 16384)
    //   V double-buffer: [16384, 24576) and [24576, 32768)
    //   Q tile:          [32768, 40960)
    //   P per-wave:      [40960, 49152)

    int t = threadIdx.x, lane = t & 63, w = t >> 6, g = lane >> 4, qi = lane & 15;
    int bb = blockIdx.y;
    int q0 = blockIdx.x * 64;
    const unsigned short* Kb = kw + (size_t)bb * 2048 * 64;
    const unsigned short* Vb = vw + (size_t)bb * 64 * 2048;
    const unsigned short* Qb = qw + ((size_t)bb * 2048 + q0) * 64;

    stage_contig((const char*)Qb, lds + 32768, w, lane);
    stage_contig((const char*)Kb, lds, w, lane);
    stage_v(Vb, 0, lds + 16384, w, lane);
    __syncthreads();

    int qrow = w * 16 + qi;
    int swq = (qrow & 7) << 4;
    bf16x8 qf0 = *(const bf16x8*)(lds + 32768 + ((qrow * 128 + g * 16) ^ swq));
    bf16x8 qf1 = *(const bf16x8*)(lds + 32768 + ((qrow * 128 + 64 + g * 16) ^ swq));

    float m_run = -INFINITY, l_run = 0.f;
    f32x4 o[4];
#pragma unroll
    for (int n = 0; n < 4; ++n) o[n] = (f32x4){0.f, 0.f, 0.f, 0.f};

    char* Pw = lds + 40960 + w * 2048;
    int swp = (qi & 7) << 4;
    int cur = 0;
    for (int kt = 0; kt < 32; ++kt) {
        if (kt + 1 < 32) {
            stage_contig((const char*)(Kb + (size_t)(kt + 1) * 4096), lds + (cur ^ 1) * 8192, w, lane);
            stage_v(Vb, (kt + 1) * 64, lds + 16384 + (cur ^ 1) * 8192, w, lane);
        }
        const char* Kt_ = lds + cur * 8192;
        const char* Vt_ = lds + 16384 + cur * 8192;

        // QK^T (swapped: D[key][q]) ; p[j] = scaled logits for q=qi, key=kb*16+g*4+r
        float p[16];
#pragma unroll
        for (int kb = 0; kb < 4; ++kb) {
            int krow = kb * 16 + qi;
            int swk = (krow & 7) << 4;
            bf16x8 ka0 = *(const bf16x8*)(Kt_ + ((krow * 128 + g * 16) ^ swk));
            bf16x8 ka1 = *(const bf16x8*)(Kt_ + ((krow * 128 + 64 + g * 16) ^ swk));
            f32x4 z = (f32x4){0.f, 0.f, 0.f, 0.f};
            z = __builtin_amdgcn_mfma_f32_16x16x32_bf16(ka0, qf0, z, 0, 0, 0);
            z = __builtin_amdgcn_mfma_f32_16x16x32_bf16(ka1, qf1, z, 0, 0, 0);
#pragma unroll
            for (int r = 0; r < 4; ++r) p[kb * 4 + r] = z[r] * 0.125f;
        }

        // online softmax (state lives at q = qi; uniform across the 4 lane-groups)
        float tmax = p[0];
#pragma unroll
        for (int j = 1; j < 16; ++j) tmax = fmaxf(tmax, p[j]);
        tmax = fmaxf(tmax, __shfl_xor(tmax, 16));
        tmax = fmaxf(tmax, __shfl_xor(tmax, 32));
        float m_new = fmaxf(m_run, tmax);
        float alpha = exp2f((m_run - m_new) * 1.44269504f);
        float lp = 0.f;
        ushort4_t pk[4];
#pragma unroll
        for (int kb = 0; kb < 4; ++kb) {
#pragma unroll
            for (int r = 0; r < 4; ++r) {
                float pv = exp2f((p[kb * 4 + r] - m_new) * 1.44269504f);
                lp += pv;
                pk[kb][r] = f2bf(pv);
            }
        }
        l_run = l_run * alpha + lp;
        m_run = m_new;

        // rescale O (O rows are q = g*4+r -> fetch their alphas from lanes 0..15)
        float a0 = __shfl(alpha, g * 4 + 0);
        float a1 = __shfl(alpha, g * 4 + 1);
        float a2 = __shfl(alpha, g * 4 + 2);
        float a3 = __shfl(alpha, g * 4 + 3);
#pragma unroll
        for (int n = 0; n < 4; ++n) {
            o[n][0] *= a0; o[n][1] *= a1; o[n][2] *= a2; o[n][3] *= a3;
        }

        // P -> per-wave LDS (re-fragment for PV)
#pragma unroll
        for (int kb = 0; kb < 4; ++kb)
            *(ushort4_t*)(Pw + ((qi * 128 + kb * 32 + g * 8) ^ swp)) = pk[kb];
        asm volatile("s_waitcnt lgkmcnt(0)" ::: "memory");
        __builtin_amdgcn_sched_barrier(0);

        // PV: O[q][h] += P[q][k] * V[k][h]
#pragma unroll
        for (int ks = 0; ks < 2; ++ks) {
            bf16x8 pa = *(const bf16x8*)(Pw + ((qi * 128 + ks * 64 + g * 16) ^ swp));
#pragma unroll
            for (int n = 0; n < 4; ++n) {
                int vrow = n * 16 + qi;
                bf16x8 vb2 = *(const bf16x8*)(Vt_ + ((vrow * 128 + ks * 64 + g * 16) ^ ((vrow & 7) << 4)));
                o[n] = __builtin_amdgcn_mfma_f32_16x16x32_bf16(pa, vb2, o[n], 0, 0, 0);
            }
        }
        __syncthreads();
        cur ^= 1;
    }

    float lt = l_run;
    lt += __shfl_xor(lt, 16);
    lt += __shfl_xor(lt, 32);
    float inv = 1.0f / lt;
    float iv0 = __shfl(inv, g * 4 + 0);
    float iv1 = __shfl(inv, g * 4 + 1);
    float iv2 = __shfl(inv, g * 4 + 2);
    float iv3 = __shfl(inv, g * 4 + 3);
    float iv[4] = {iv0, iv1, iv2, iv3};
#pragma unroll
    for (int r = 0; r < 4; ++r) {
        size_t base = ((size_t)(bb * 2048 + q0 + w * 16 + g * 4 + r)) * 64;
#pragma unroll
        for (int n = 0; n < 4; ++n) out[base + n * 16 + qi] = o[n][r] * iv[r];
    }
}

extern "C" void kernel_launch(void* const* d_in, const int* in_sizes, int n_in,
                              void* d_out, int out_size, void* d_ws, size_t ws_size,
                              hipStream_t stream) {
    const float* x  = (const float*)d_in[0];
    const float* Wq = (const float*)d_in[1];
    const float* Wk = (const float*)d_in[2];
    const float* Wv = (const float*)d_in[3];
    char* ws = (char*)d_ws;
    unsigned short* Wt = (unsigned short*)ws;                       // 3*64*1024*2   = 384KB
    unsigned short* qw = (unsigned short*)(ws + 393216);            // [16384][64]   = 2MB
    unsigned short* kw = (unsigned short*)(ws + 393216 + 2097152);  // [16384][64]   = 2MB
    unsigned short* vw = (unsigned short*)(ws + 393216 + 4194304);  // [8][64][2048] = 2MB
    float* out = (float*)d_out;

    hipLaunchKernelGGL(prep_w_kernel, dim3(16, 3), dim3(256), 0, stream, Wq, Wk, Wv, Wt);
    hipLaunchKernelGGL(qkv_kernel, dim3(256), dim3(256), 0, stream, x, Wt, qw, kw, vw);
    hipLaunchKernelGGL(attn_kernel, dim3(32, 8), dim3(256), 0, stream, qw, kw, vw, out);
}

// Round 3
// 67.469 us; speedup vs baseline: 1.0554x; 1.0554x over previous
//
#include <hip/hip_runtime.h>
#include <hip/hip_bf16.h>
#include <math.h>

typedef float f32x4 __attribute__((ext_vector_type(4)));
typedef __bf16 bf16x8 __attribute__((ext_vector_type(8)));
typedef unsigned short ushort4_t __attribute__((ext_vector_type(4)));

#define B_ 8
#define S_ 2048
#define D_ 1024
#define H_ 64
#define M_ (B_*S_)   // 16384

static __device__ __forceinline__ unsigned short f2bf(float f) {
    __bf16 h = (__bf16)f;
    return __builtin_bit_cast(unsigned short, h);
}

static __device__ __forceinline__ void gload16(const void* g, void* l) {
    __builtin_amdgcn_global_load_lds(
        (__attribute__((address_space(1))) void*)(void*)g,
        (__attribute__((address_space(3))) void*)l, 16, 0, 0);
}

// Stage a contiguous 8KB global region into LDS with inverse-swizzled SOURCE so
// that reads with byte ^ ((row&7)<<4) (row = byte>>7, 128B rows) see logical data.
static __device__ __forceinline__ void stage_contig(const char* gsrc, char* dst, int w, int lane) {
#pragma unroll
    for (int i = 0; i < 2; ++i) {
        int ch = w * 128 + i * 64 + lane;
        int p = ch * 16;
        int so = p ^ (((p >> 7) & 7) << 4);
        gload16(gsrc + so, dst + (w * 128 + i * 64) * 16);
    }
}

// Stage a [64 rows][128B] tile whose global rows are strided (vT: 4096B stride).
static __device__ __forceinline__ void stage_v(const unsigned short* Vb, int k0, char* dst, int w, int lane) {
#pragma unroll
    for (int i = 0; i < 2; ++i) {
        int ch = w * 128 + i * 64 + lane;
        int p = ch * 16;
        int rr = p >> 7;
        int off = (p ^ ((rr & 7) << 4)) & 127;
        const char* gsrc = (const char*)(Vb + (size_t)rr * 2048 + k0) + off;
        gload16(gsrc, dst + (w * 128 + i * 64) * 16);
    }
}

// Stage Wt tile: 192 rows x 128B, global row stride 2048B. 1536 chunks, 6 per wave-lane.
static __device__ __forceinline__ void stage_wt(const unsigned short* Wt, int kt, char* dst, int w, int lane) {
#pragma unroll
    for (int i = 0; i < 6; ++i) {
        int ch = w * 384 + i * 64 + lane;
        int p = ch * 16;
        int rr = p >> 7;
        int off = (p ^ ((rr & 7) << 4)) & 127;
        const char* gsrc = (const char*)Wt + (size_t)rr * 2048 + kt * 128 + off;
        gload16(gsrc, dst + (w * 384 + i * 64) * 16);
    }
}

// ---------------- Kernel 0: W [1024][64] f32 -> Wt [3][64][1024] bf16 ----------------
__global__ __launch_bounds__(256) void prep_w_kernel(const float* __restrict__ Wq,
                                                     const float* __restrict__ Wk,
                                                     const float* __restrict__ Wv,
                                                     unsigned short* __restrict__ Wt) {
    __shared__ float tile[64][65];
    int which = blockIdx.y;
    const float* W = (which == 0) ? Wq : ((which == 1) ? Wk : Wv);
    int k0 = blockIdx.x * 64;
    int t = threadIdx.x;
    int r = t >> 2, c0 = (t & 3) * 16;
#pragma unroll
    for (int j = 0; j < 16; ++j) tile[r][c0 + j] = W[(size_t)(k0 + r) * 64 + c0 + j];
    __syncthreads();
    unsigned short* dst = Wt + (size_t)(which * 64 + r) * 1024 + k0 + c0;
#pragma unroll
    for (int j = 0; j < 16; ++j) dst[j] = f2bf(tile[c0 + j][r]);
}

// ---------------- Kernel 1: qkv projection ----------------
// out: qw,kw natural [M][64] bf16 ; vw transposed [B][64][2048] bf16
__global__ __launch_bounds__(256) void qkv_kernel(const float* __restrict__ x,
                                                  const unsigned short* __restrict__ Wt,
                                                  unsigned short* __restrict__ qw,
                                                  unsigned short* __restrict__ kw,
                                                  unsigned short* __restrict__ vw) {
    __shared__ __align__(16) char lds[8192 + 2 * 24576];
    char* xs = lds;
    int t = threadIdx.x, lane = t & 63, w = t >> 6, g = lane >> 4, qi = lane & 15;
    int m0 = blockIdx.x * 64;
    int row = t >> 2, kc = (t & 3) * 16;
    const float* xrow = x + (size_t)(m0 + row) * 1024 + kc;

    f32x4 acc[12];
#pragma unroll
    for (int n = 0; n < 12; ++n) acc[n] = (f32x4){0.f, 0.f, 0.f, 0.f};

    // prologue: x tile0 -> regs, Wt tile0 -> LDS buf0
    float4 xr0 = *(const float4*)(xrow + 0);
    float4 xr1 = *(const float4*)(xrow + 4);
    float4 xr2 = *(const float4*)(xrow + 8);
    float4 xr3 = *(const float4*)(xrow + 12);
    stage_wt(Wt, 0, lds + 8192, w, lane);

    int cur = 0;
    for (int kt = 0; kt < 16; ++kt) {
        // write xs from regs (swizzled both sides)
        bf16x8 lo, hi;
        lo[0] = (__bf16)xr0.x; lo[1] = (__bf16)xr0.y; lo[2] = (__bf16)xr0.z; lo[3] = (__bf16)xr0.w;
        lo[4] = (__bf16)xr1.x; lo[5] = (__bf16)xr1.y; lo[6] = (__bf16)xr1.z; lo[7] = (__bf16)xr1.w;
        hi[0] = (__bf16)xr2.x; hi[1] = (__bf16)xr2.y; hi[2] = (__bf16)xr2.z; hi[3] = (__bf16)xr2.w;
        hi[4] = (__bf16)xr3.x; hi[5] = (__bf16)xr3.y; hi[6] = (__bf16)xr3.z; hi[7] = (__bf16)xr3.w;
        int b0 = row * 128 + kc * 2;
        int sw = (row & 7) << 4;
        *(bf16x8*)(xs + (b0 ^ sw)) = lo;
        *(bf16x8*)(xs + ((b0 + 16) ^ sw)) = hi;
        __syncthreads();  // xs visible; Wt(kt) vmcnt-drained

        if (kt < 15) {
            const float* nsrc = xrow + (kt + 1) * 64;
            xr0 = *(const float4*)(nsrc + 0);
            xr1 = *(const float4*)(nsrc + 4);
            xr2 = *(const float4*)(nsrc + 8);
            xr3 = *(const float4*)(nsrc + 12);
            stage_wt(Wt, kt + 1, lds + 8192 + (cur ^ 1) * 24576, w, lane);
        }
        const char* wsb = lds + 8192 + cur * 24576;

        int arow = w * 16 + qi;
        int swa = (arow & 7) << 4;
#pragma unroll
        for (int ks = 0; ks < 2; ++ks) {
            bf16x8 a = *(const bf16x8*)(xs + ((arow * 128 + ks * 64 + g * 16) ^ swa));
#pragma unroll
            for (int n = 0; n < 12; ++n) {
                int brow = n * 16 + qi;
                bf16x8 bb = *(const bf16x8*)(wsb + ((brow * 128 + ks * 64 + g * 16) ^ ((brow & 7) << 4)));
                acc[n] = __builtin_amdgcn_mfma_f32_16x16x32_bf16(a, bb, acc[n], 0, 0, 0);
            }
        }
        __syncthreads();
        cur ^= 1;
    }

    // epilogue: D layout col=lane&15, row=(lane>>4)*4+reg
    int bq = m0 >> 11;             // batch
    int sl = (m0 & 2047) + w * 16 + g * 4;  // s within batch
#pragma unroll
    for (int n = 0; n < 12; ++n) {
        int col = (n & 3) * 16 + qi;
        int which = n >> 2;
        if (which == 0) {
#pragma unroll
            for (int r = 0; r < 4; ++r)
                qw[(size_t)(m0 + w * 16 + g * 4 + r) * 64 + col] = f2bf(acc[n][r]);
        } else if (which == 1) {
#pragma unroll
            for (int r = 0; r < 4; ++r)
                kw[(size_t)(m0 + w * 16 + g * 4 + r) * 64 + col] = f2bf(acc[n][r]);
        } else {
            ushort4_t pv;
            pv[0] = f2bf(acc[n][0]); pv[1] = f2bf(acc[n][1]);
            pv[2] = f2bf(acc[n][2]); pv[3] = f2bf(acc[n][3]);
            *(ushort4_t*)(vw + (size_t)bq * 64 * 2048 + (size_t)col * 2048 + sl) = pv;
        }
    }
}

// ---------------- Kernel 2: flash attention, KV-split ----------------
// Writes UNNORMALIZED partial O + per-row (m, l) for each split.
// LDS: K dbuf [0,16384), V dbuf [16384,32768), P per-wave [32768,40960) = 40KB
__global__ __launch_bounds__(256) void attn_kernel(const unsigned short* __restrict__ qw,
                                                   const unsigned short* __restrict__ kw,
                                                   const unsigned short* __restrict__ vw,
                                                   float* __restrict__ Op,
                                                   float* __restrict__ mbuf,
                                                   float* __restrict__ lbuf,
                                                   int nkt) {
    __shared__ __align__(16) char lds[40960];

    int t = threadIdx.x, lane = t & 63, w = t >> 6, g = lane >> 4, qi = lane & 15;
    int bb = blockIdx.y;
    int q0 = blockIdx.x * 64;
    int sp = blockIdx.z;
    int kt0 = sp * nkt;
    const unsigned short* Kb = kw + (size_t)bb * 2048 * 64;
    const unsigned short* Vb = vw + (size_t)bb * 64 * 2048;
    const unsigned short* Qb = qw + ((size_t)bb * 2048 + q0) * 64;

    // Q fragments directly global->reg (each row read once)
    int qrow = w * 16 + qi;
    const unsigned short* Qr = Qb + (size_t)qrow * 64;
    bf16x8 qf0 = *(const bf16x8*)(Qr + g * 8);
    bf16x8 qf1 = *(const bf16x8*)(Qr + 32 + g * 8);

    stage_contig((const char*)(Kb + (size_t)kt0 * 4096), lds, w, lane);
    stage_v(Vb, kt0 * 64, lds + 16384, w, lane);
    __syncthreads();

    float m_run = -INFINITY, l_run = 0.f;
    f32x4 o[4];
#pragma unroll
    for (int n = 0; n < 4; ++n) o[n] = (f32x4){0.f, 0.f, 0.f, 0.f};

    char* Pw = lds + 32768 + w * 2048;
    int swp = (qi & 7) << 4;
    int cur = 0;
    for (int kt = 0; kt < nkt; ++kt) {
        if (kt + 1 < nkt) {
            stage_contig((const char*)(Kb + (size_t)(kt0 + kt + 1) * 4096), lds + (cur ^ 1) * 8192, w, lane);
            stage_v(Vb, (kt0 + kt + 1) * 64, lds + 16384 + (cur ^ 1) * 8192, w, lane);
        }
        const char* Kt_ = lds + cur * 8192;
        const char* Vt_ = lds + 16384 + cur * 8192;

        // QK^T (swapped: D[key][q]) ; p[j] = scaled logits for q=qi, key=kb*16+g*4+r
        float p[16];
        __builtin_amdgcn_s_setprio(1);
#pragma unroll
        for (int kb = 0; kb < 4; ++kb) {
            int krow = kb * 16 + qi;
            int swk = (krow & 7) << 4;
            bf16x8 ka0 = *(const bf16x8*)(Kt_ + ((krow * 128 + g * 16) ^ swk));
            bf16x8 ka1 = *(const bf16x8*)(Kt_ + ((krow * 128 + 64 + g * 16) ^ swk));
            f32x4 z = (f32x4){0.f, 0.f, 0.f, 0.f};
            z = __builtin_amdgcn_mfma_f32_16x16x32_bf16(ka0, qf0, z, 0, 0, 0);
            z = __builtin_amdgcn_mfma_f32_16x16x32_bf16(ka1, qf1, z, 0, 0, 0);
#pragma unroll
            for (int r = 0; r < 4; ++r) p[kb * 4 + r] = z[r] * 0.125f;
        }
        __builtin_amdgcn_s_setprio(0);

        // online softmax (state lives at q = qi; uniform across the 4 lane-groups)
        float tmax = p[0];
#pragma unroll
        for (int j = 1; j < 16; ++j) tmax = fmaxf(tmax, p[j]);
        tmax = fmaxf(tmax, __shfl_xor(tmax, 16));
        tmax = fmaxf(tmax, __shfl_xor(tmax, 32));
        float m_new = fmaxf(m_run, tmax);
        float alpha = exp2f((m_run - m_new) * 1.44269504f);
        float lp = 0.f;
        ushort4_t pk[4];
#pragma unroll
        for (int kb = 0; kb < 4; ++kb) {
#pragma unroll
            for (int r = 0; r < 4; ++r) {
                float pv = exp2f((p[kb * 4 + r] - m_new) * 1.44269504f);
                lp += pv;
                pk[kb][r] = f2bf(pv);
            }
        }
        l_run = l_run * alpha + lp;
        m_run = m_new;

        // rescale O (O rows are q = g*4+r -> fetch their alphas from lanes 0..15)
        float a0 = __shfl(alpha, g * 4 + 0);
        float a1 = __shfl(alpha, g * 4 + 1);
        float a2 = __shfl(alpha, g * 4 + 2);
        float a3 = __shfl(alpha, g * 4 + 3);
#pragma unroll
        for (int n = 0; n < 4; ++n) {
            o[n][0] *= a0; o[n][1] *= a1; o[n][2] *= a2; o[n][3] *= a3;
        }

        // P -> per-wave LDS (re-fragment for PV)
#pragma unroll
        for (int kb = 0; kb < 4; ++kb)
            *(ushort4_t*)(Pw + ((qi * 128 + kb * 32 + g * 8) ^ swp)) = pk[kb];
        asm volatile("s_waitcnt lgkmcnt(0)" ::: "memory");
        __builtin_amdgcn_sched_barrier(0);

        // PV: O[q][h] += P[q][k] * V[k][h]
        __builtin_amdgcn_s_setprio(1);
#pragma unroll
        for (int ks = 0; ks < 2; ++ks) {
            bf16x8 pa = *(const bf16x8*)(Pw + ((qi * 128 + ks * 64 + g * 16) ^ swp));
#pragma unroll
            for (int n = 0; n < 4; ++n) {
                int vrow = n * 16 + qi;
                bf16x8 vb2 = *(const bf16x8*)(Vt_ + ((vrow * 128 + ks * 64 + g * 16) ^ ((vrow & 7) << 4)));
                o[n] = __builtin_amdgcn_mfma_f32_16x16x32_bf16(pa, vb2, o[n], 0, 0, 0);
            }
        }
        __builtin_amdgcn_s_setprio(0);
        __syncthreads();
        cur ^= 1;
    }

    // partial l: sum the 4 per-group partials; m is already uniform
    float lt = l_run;
    lt += __shfl_xor(lt, 16);
    lt += __shfl_xor(lt, 32);
    size_t rowbase = (size_t)sp * 16384 + bb * 2048 + q0 + w * 16;
    if (g == 0) {
        mbuf[rowbase + qi] = m_run;
        lbuf[rowbase + qi] = lt;
    }
#pragma unroll
    for (int r = 0; r < 4; ++r) {
        size_t base = (rowbase + g * 4 + r) * 64;
#pragma unroll
        for (int n = 0; n < 4; ++n) Op[base + n * 16 + qi] = o[n][r];
    }
}

// ---------------- Kernel 3: split combine ----------------
__global__ __launch_bounds__(256) void combine_kernel(const float* __restrict__ Op,
                                                      const float* __restrict__ mbuf,
                                                      const float* __restrict__ lbuf,
                                                      float* __restrict__ out,
                                                      int nsplit) {
    int row = blockIdx.x * 4 + (threadIdx.x >> 6);
    int col = threadIdx.x & 63;
    float M = -INFINITY;
    for (int s = 0; s < nsplit; ++s) M = fmaxf(M, mbuf[s * 16384 + row]);
    float L = 0.f, acc = 0.f;
    for (int s = 0; s < nsplit; ++s) {
        float wgt = exp2f((mbuf[s * 16384 + row] - M) * 1.44269504f);
        L += lbuf[s * 16384 + row] * wgt;
        acc += Op[((size_t)s * 16384 + row) * 64 + col] * wgt;
    }
    out[(size_t)row * 64 + col] = acc / L;
}

extern "C" void kernel_launch(void* const* d_in, const int* in_sizes, int n_in,
                              void* d_out, int out_size, void* d_ws, size_t ws_size,
                              hipStream_t stream) {
    const float* x  = (const float*)d_in[0];
    const float* Wq = (const float*)d_in[1];
    const float* Wk = (const float*)d_in[2];
    const float* Wv = (const float*)d_in[3];
    char* ws = (char*)d_ws;
    unsigned short* Wt = (unsigned short*)ws;                       // 3*64*1024*2   = 384KB
    unsigned short* qw = (unsigned short*)(ws + 393216);            // [16384][64]   = 2MB
    unsigned short* kw = (unsigned short*)(ws + 393216 + 2097152);  // [16384][64]   = 2MB
    unsigned short* vw = (unsigned short*)(ws + 393216 + 4194304);  // [8][64][2048] = 2MB
    float* out = (float*)d_out;

    const size_t base = 393216 + 3 * 2097152;  // 6684672
    const size_t per_split = 16384ULL * 64 * 4 + 2 * 16384ULL * 4;  // Op + m + l = 4325376
    int nsplit = 1;
    if (ws_size >= base + 4 * per_split) nsplit = 4;
    else if (ws_size >= base + 2 * per_split) nsplit = 2;
    int nkt = 32 / nsplit;

    float* Op   = (float*)(ws + base);
    float* mbuf = (float*)(ws + base + (size_t)nsplit * 16384 * 64 * 4);
    float* lbuf = mbuf + (size_t)nsplit * 16384;

    hipLaunchKernelGGL(prep_w_kernel, dim3(16, 3), dim3(256), 0, stream, Wq, Wk, Wv, Wt);
    hipLaunchKernelGGL(qkv_kernel, dim3(256), dim3(256), 0, stream, x, Wt, qw, kw, vw);
    hipLaunchKernelGGL(attn_kernel, dim3(32, 8, nsplit), dim3(256), 0, stream,
                       qw, kw, vw, Op, mbuf, lbuf, nkt);
    hipLaunchKernelGGL(combine_kernel, dim3(4096), dim3(256), 0, stream,
                       Op, mbuf, lbuf, out, nsplit);
}

// Round 4
// 61.032 us; speedup vs baseline: 1.1668x; 1.1055x over previous
//
#include <hip/hip_runtime.h>
#include <hip/hip_bf16.h>
#include <math.h>

typedef float f32x4 __attribute__((ext_vector_type(4)));
typedef __bf16 bf16x8 __attribute__((ext_vector_type(8)));
typedef unsigned short ushort4_t __attribute__((ext_vector_type(4)));

#define B_ 8
#define S_ 2048
#define D_ 1024
#define H_ 64
#define M_ (B_*S_)   // 16384

static __device__ __forceinline__ unsigned short f2bf(float f) {
    __bf16 h = (__bf16)f;
    return __builtin_bit_cast(unsigned short, h);
}

static __device__ __forceinline__ void gload16(const void* g, void* l) {
    __builtin_amdgcn_global_load_lds(
        (__attribute__((address_space(1))) void*)(void*)g,
        (__attribute__((address_space(3))) void*)l, 16, 0, 0);
}

// Stage a contiguous 8KB global region into LDS with inverse-swizzled SOURCE so
// that reads with byte ^ ((row&7)<<4) (row = byte>>7, 128B rows) see logical data.
static __device__ __forceinline__ void stage_contig(const char* gsrc, char* dst, int w, int lane) {
#pragma unroll
    for (int i = 0; i < 2; ++i) {
        int ch = w * 128 + i * 64 + lane;
        int p = ch * 16;
        int so = p ^ (((p >> 7) & 7) << 4);
        gload16(gsrc + so, dst + (w * 128 + i * 64) * 16);
    }
}

// Stage a [64 rows][128B] tile whose global rows are strided (vT: 4096B stride).
static __device__ __forceinline__ void stage_v(const unsigned short* Vb, int k0, char* dst, int w, int lane) {
#pragma unroll
    for (int i = 0; i < 2; ++i) {
        int ch = w * 128 + i * 64 + lane;
        int p = ch * 16;
        int rr = p >> 7;
        int off = (p ^ ((rr & 7) << 4)) & 127;
        const char* gsrc = (const char*)(Vb + (size_t)rr * 2048 + k0) + off;
        gload16(gsrc, dst + (w * 128 + i * 64) * 16);
    }
}

// Stage Wt tile: 192 rows x 128B, global row stride 2048B. 1536 chunks, 6 per wave-lane.
static __device__ __forceinline__ void stage_wt(const unsigned short* Wt, int kt, char* dst, int w, int lane) {
#pragma unroll
    for (int i = 0; i < 6; ++i) {
        int ch = w * 384 + i * 64 + lane;
        int p = ch * 16;
        int rr = p >> 7;
        int off = (p ^ ((rr & 7) << 4)) & 127;
        const char* gsrc = (const char*)Wt + (size_t)rr * 2048 + kt * 128 + off;
        gload16(gsrc, dst + (w * 384 + i * 64) * 16);
    }
}

// ---------------- Kernel 0: W [1024][64] f32 -> Wt [3][64][1024] bf16 ----------------
__global__ __launch_bounds__(256) void prep_w_kernel(const float* __restrict__ Wq,
                                                     const float* __restrict__ Wk,
                                                     const float* __restrict__ Wv,
                                                     unsigned short* __restrict__ Wt) {
    __shared__ float tile[64][65];
    int which = blockIdx.y;
    const float* W = (which == 0) ? Wq : ((which == 1) ? Wk : Wv);
    int k0 = blockIdx.x * 64;
    int t = threadIdx.x;
    int r = t >> 2, c0 = (t & 3) * 16;
#pragma unroll
    for (int j = 0; j < 16; ++j) tile[r][c0 + j] = W[(size_t)(k0 + r) * 64 + c0 + j];
    __syncthreads();
    unsigned short* dst = Wt + (size_t)(which * 64 + r) * 1024 + k0 + c0;
#pragma unroll
    for (int j = 0; j < 16; ++j) dst[j] = f2bf(tile[c0 + j][r]);
}

// ---------------- Kernel 1: qkv projection, 32-row M-tiles ----------------
// out: qw,kw natural [M][64] bf16 ; vw transposed [B][64][2048] bf16
// Block: 256 thr / 4 waves; wave (w&1)=row-half(16), (w>>1)=col-half(96 cols).
// LDS: xs [0,4096) ; Wt dbuf [4096, 4096+2*24576) = 53248 B -> 3 blocks/CU.
__global__ __launch_bounds__(256) void qkv_kernel(const float* __restrict__ x,
                                                  const unsigned short* __restrict__ Wt,
                                                  unsigned short* __restrict__ qw,
                                                  unsigned short* __restrict__ kw,
                                                  unsigned short* __restrict__ vw) {
    __shared__ __align__(16) char lds[4096 + 2 * 24576];
    char* xs = lds;
    int t = threadIdx.x, lane = t & 63, w = t >> 6, g = lane >> 4, qi = lane & 15;
    int m0 = blockIdx.x * 32;
    int row = t >> 3, seg = t & 7;
    const float* xrow = x + (size_t)(m0 + row) * 1024 + seg * 8;

    f32x4 acc[6];
#pragma unroll
    for (int n = 0; n < 6; ++n) acc[n] = (f32x4){0.f, 0.f, 0.f, 0.f};

    // prologue: x tile0 -> regs, Wt tile0 -> LDS buf0
    float4 xr0 = *(const float4*)(xrow + 0);
    float4 xr1 = *(const float4*)(xrow + 4);
    stage_wt(Wt, 0, lds + 4096, w, lane);

    int rh = w & 1, ch = w >> 1;
    int cur = 0;
    for (int kt = 0; kt < 16; ++kt) {
        // write xs from regs (swizzled both sides): 16B per thread
        bf16x8 pk;
        pk[0] = (__bf16)xr0.x; pk[1] = (__bf16)xr0.y; pk[2] = (__bf16)xr0.z; pk[3] = (__bf16)xr0.w;
        pk[4] = (__bf16)xr1.x; pk[5] = (__bf16)xr1.y; pk[6] = (__bf16)xr1.z; pk[7] = (__bf16)xr1.w;
        int b0 = row * 128 + seg * 16;
        *(bf16x8*)(xs + (b0 ^ ((row & 7) << 4))) = pk;
        __syncthreads();  // xs visible; Wt(kt) vmcnt-drained

        if (kt < 15) {
            const float* nsrc = xrow + (kt + 1) * 64;
            xr0 = *(const float4*)(nsrc + 0);
            xr1 = *(const float4*)(nsrc + 4);
            stage_wt(Wt, kt + 1, lds + 4096 + (cur ^ 1) * 24576, w, lane);
        }
        const char* wsb = lds + 4096 + cur * 24576;

        int arow = rh * 16 + qi;
        int swa = (arow & 7) << 4;
#pragma unroll
        for (int ks = 0; ks < 2; ++ks) {
            bf16x8 a = *(const bf16x8*)(xs + ((arow * 128 + ks * 64 + g * 16) ^ swa));
#pragma unroll
            for (int n = 0; n < 6; ++n) {
                int brow = ch * 96 + n * 16 + qi;
                bf16x8 bb = *(const bf16x8*)(wsb + ((brow * 128 + ks * 64 + g * 16) ^ ((brow & 7) << 4)));
                acc[n] = __builtin_amdgcn_mfma_f32_16x16x32_bf16(a, bb, acc[n], 0, 0, 0);
            }
        }
        __syncthreads();
        cur ^= 1;
    }

    // epilogue: D layout col=lane&15, row=(lane>>4)*4+reg
    int bq = m0 >> 11;                        // batch
    int sl = (m0 & 2047) + rh * 16 + g * 4;   // s within batch (v path)
    int rowg = m0 + rh * 16 + g * 4;          // global row (q/k paths)
#pragma unroll
    for (int n = 0; n < 6; ++n) {
        int c = ch * 96 + n * 16;             // wave-uniform
        int which = c >> 6;
        int col = (c & 63) + qi;
        if (which == 0) {
#pragma unroll
            for (int r = 0; r < 4; ++r)
                qw[(size_t)(rowg + r) * 64 + col] = f2bf(acc[n][r]);
        } else if (which == 1) {
#pragma unroll
            for (int r = 0; r < 4; ++r)
                kw[(size_t)(rowg + r) * 64 + col] = f2bf(acc[n][r]);
        } else {
            ushort4_t pv;
            pv[0] = f2bf(acc[n][0]); pv[1] = f2bf(acc[n][1]);
            pv[2] = f2bf(acc[n][2]); pv[3] = f2bf(acc[n][3]);
            *(ushort4_t*)(vw + (size_t)bq * 64 * 2048 + (size_t)col * 2048 + sl) = pv;
        }
    }
}

// ---------------- Kernel 2: flash attention, KV-split ----------------
// Writes UNNORMALIZED partial O + per-row (m, l) for each split.
// LDS: K dbuf [0,16384), V dbuf [16384,32768), P per-wave [32768,40960) = 40KB
__global__ __launch_bounds__(256) void attn_kernel(const unsigned short* __restrict__ qw,
                                                   const unsigned short* __restrict__ kw,
                                                   const unsigned short* __restrict__ vw,
                                                   float* __restrict__ Op,
                                                   float* __restrict__ mbuf,
                                                   float* __restrict__ lbuf,
                                                   int nkt) {
    __shared__ __align__(16) char lds[40960];

    int t = threadIdx.x, lane = t & 63, w = t >> 6, g = lane >> 4, qi = lane & 15;
    int bb = blockIdx.y;
    int q0 = blockIdx.x * 64;
    int sp = blockIdx.z;
    int kt0 = sp * nkt;
    const unsigned short* Kb = kw + (size_t)bb * 2048 * 64;
    const unsigned short* Vb = vw + (size_t)bb * 64 * 2048;
    const unsigned short* Qb = qw + ((size_t)bb * 2048 + q0) * 64;

    // Q fragments directly global->reg (each row read once)
    int qrow = w * 16 + qi;
    const unsigned short* Qr = Qb + (size_t)qrow * 64;
    bf16x8 qf0 = *(const bf16x8*)(Qr + g * 8);
    bf16x8 qf1 = *(const bf16x8*)(Qr + 32 + g * 8);

    stage_contig((const char*)(Kb + (size_t)kt0 * 4096), lds, w, lane);
    stage_v(Vb, kt0 * 64, lds + 16384, w, lane);
    __syncthreads();

    float m_run = -INFINITY, l_run = 0.f;
    f32x4 o[4];
#pragma unroll
    for (int n = 0; n < 4; ++n) o[n] = (f32x4){0.f, 0.f, 0.f, 0.f};

    char* Pw = lds + 32768 + w * 2048;
    int swp = (qi & 7) << 4;
    int cur = 0;
    for (int kt = 0; kt < nkt; ++kt) {
        if (kt + 1 < nkt) {
            stage_contig((const char*)(Kb + (size_t)(kt0 + kt + 1) * 4096), lds + (cur ^ 1) * 8192, w, lane);
            stage_v(Vb, (kt0 + kt + 1) * 64, lds + 16384 + (cur ^ 1) * 8192, w, lane);
        }
        const char* Kt_ = lds + cur * 8192;
        const char* Vt_ = lds + 16384 + cur * 8192;

        // QK^T (swapped: D[key][q]) ; p[j] = scaled logits for q=qi, key=kb*16+g*4+r
        float p[16];
        __builtin_amdgcn_s_setprio(1);
#pragma unroll
        for (int kb = 0; kb < 4; ++kb) {
            int krow = kb * 16 + qi;
            int swk = (krow & 7) << 4;
            bf16x8 ka0 = *(const bf16x8*)(Kt_ + ((krow * 128 + g * 16) ^ swk));
            bf16x8 ka1 = *(const bf16x8*)(Kt_ + ((krow * 128 + 64 + g * 16) ^ swk));
            f32x4 z = (f32x4){0.f, 0.f, 0.f, 0.f};
            z = __builtin_amdgcn_mfma_f32_16x16x32_bf16(ka0, qf0, z, 0, 0, 0);
            z = __builtin_amdgcn_mfma_f32_16x16x32_bf16(ka1, qf1, z, 0, 0, 0);
#pragma unroll
            for (int r = 0; r < 4; ++r) p[kb * 4 + r] = z[r] * 0.125f;
        }
        __builtin_amdgcn_s_setprio(0);

        // online softmax (state lives at q = qi; uniform across the 4 lane-groups)
        float tmax = p[0];
#pragma unroll
        for (int j = 1; j < 16; ++j) tmax = fmaxf(tmax, p[j]);
        tmax = fmaxf(tmax, __shfl_xor(tmax, 16));
        tmax = fmaxf(tmax, __shfl_xor(tmax, 32));
        float m_new = fmaxf(m_run, tmax);
        float alpha = exp2f((m_run - m_new) * 1.44269504f);
        float lp = 0.f;
        ushort4_t pk[4];
#pragma unroll
        for (int kb = 0; kb < 4; ++kb) {
#pragma unroll
            for (int r = 0; r < 4; ++r) {
                float pv = exp2f((p[kb * 4 + r] - m_new) * 1.44269504f);
                lp += pv;
                pk[kb][r] = f2bf(pv);
            }
        }
        l_run = l_run * alpha + lp;
        m_run = m_new;

        // rescale O (O rows are q = g*4+r -> fetch their alphas from lanes 0..15)
        float a0 = __shfl(alpha, g * 4 + 0);
        float a1 = __shfl(alpha, g * 4 + 1);
        float a2 = __shfl(alpha, g * 4 + 2);
        float a3 = __shfl(alpha, g * 4 + 3);
#pragma unroll
        for (int n = 0; n < 4; ++n) {
            o[n][0] *= a0; o[n][1] *= a1; o[n][2] *= a2; o[n][3] *= a3;
        }

        // P -> per-wave LDS (re-fragment for PV)
#pragma unroll
        for (int kb = 0; kb < 4; ++kb)
            *(ushort4_t*)(Pw + ((qi * 128 + kb * 32 + g * 8) ^ swp)) = pk[kb];
        asm volatile("s_waitcnt lgkmcnt(0)" ::: "memory");
        __builtin_amdgcn_sched_barrier(0);

        // PV: O[q][h] += P[q][k] * V[k][h]
        __builtin_amdgcn_s_setprio(1);
#pragma unroll
        for (int ks = 0; ks < 2; ++ks) {
            bf16x8 pa = *(const bf16x8*)(Pw + ((qi * 128 + ks * 64 + g * 16) ^ swp));
#pragma unroll
            for (int n = 0; n < 4; ++n) {
                int vrow = n * 16 + qi;
                bf16x8 vb2 = *(const bf16x8*)(Vt_ + ((vrow * 128 + ks * 64 + g * 16) ^ ((vrow & 7) << 4)));
                o[n] = __builtin_amdgcn_mfma_f32_16x16x32_bf16(pa, vb2, o[n], 0, 0, 0);
            }
        }
        __builtin_amdgcn_s_setprio(0);
        __syncthreads();
        cur ^= 1;
    }

    // partial l: sum the 4 per-group partials; m is already uniform
    float lt = l_run;
    lt += __shfl_xor(lt, 16);
    lt += __shfl_xor(lt, 32);
    size_t rowbase = (size_t)sp * 16384 + bb * 2048 + q0 + w * 16;
    if (g == 0) {
        mbuf[rowbase + qi] = m_run;
        lbuf[rowbase + qi] = lt;
    }
#pragma unroll
    for (int r = 0; r < 4; ++r) {
        size_t base = (rowbase + g * 4 + r) * 64;
#pragma unroll
        for (int n = 0; n < 4; ++n) Op[base + n * 16 + qi] = o[n][r];
    }
}

// ---------------- Kernel 3: split combine ----------------
__global__ __launch_bounds__(256) void combine_kernel(const float* __restrict__ Op,
                                                      const float* __restrict__ mbuf,
                                                      const float* __restrict__ lbuf,
                                                      float* __restrict__ out,
                                                      int nsplit) {
    int row = blockIdx.x * 4 + (threadIdx.x >> 6);
    int col = threadIdx.x & 63;
    float M = -INFINITY;
    for (int s = 0; s < nsplit; ++s) M = fmaxf(M, mbuf[s * 16384 + row]);
    float L = 0.f, acc = 0.f;
    for (int s = 0; s < nsplit; ++s) {
        float wgt = exp2f((mbuf[s * 16384 + row] - M) * 1.44269504f);
        L += lbuf[s * 16384 + row] * wgt;
        acc += Op[((size_t)s * 16384 + row) * 64 + col] * wgt;
    }
    out[(size_t)row * 64 + col] = acc / L;
}

extern "C" void kernel_launch(void* const* d_in, const int* in_sizes, int n_in,
                              void* d_out, int out_size, void* d_ws, size_t ws_size,
                              hipStream_t stream) {
    const float* x  = (const float*)d_in[0];
    const float* Wq = (const float*)d_in[1];
    const float* Wk = (const float*)d_in[2];
    const float* Wv = (const float*)d_in[3];
    char* ws = (char*)d_ws;
    unsigned short* Wt = (unsigned short*)ws;                       // 3*64*1024*2   = 384KB
    unsigned short* qw = (unsigned short*)(ws + 393216);            // [16384][64]   = 2MB
    unsigned short* kw = (unsigned short*)(ws + 393216 + 2097152);  // [16384][64]   = 2MB
    unsigned short* vw = (unsigned short*)(ws + 393216 + 4194304);  // [8][64][2048] = 2MB
    float* out = (float*)d_out;

    const size_t base = 393216 + 3 * 2097152;  // 6684672
    const size_t per_split = 16384ULL * 64 * 4 + 2 * 16384ULL * 4;  // Op + m + l = 4325376
    int nsplit = 1;
    if (ws_size >= base + 4 * per_split) nsplit = 4;
    else if (ws_size >= base + 2 * per_split) nsplit = 2;
    int nkt = 32 / nsplit;

    float* Op   = (float*)(ws + base);
    float* mbuf = (float*)(ws + base + (size_t)nsplit * 16384 * 64 * 4);
    float* lbuf = mbuf + (size_t)nsplit * 16384;

    hipLaunchKernelGGL(prep_w_kernel, dim3(16, 3), dim3(256), 0, stream, Wq, Wk, Wv, Wt);
    hipLaunchKernelGGL(qkv_kernel, dim3(512), dim3(256), 0, stream, x, Wt, qw, kw, vw);
    hipLaunchKernelGGL(attn_kernel, dim3(32, 8, nsplit), dim3(256), 0, stream,
                       qw, kw, vw, Op, mbuf, lbuf, nkt);
    hipLaunchKernelGGL(combine_kernel, dim3(4096), dim3(256), 0, stream,
                       Op, mbuf, lbuf, out, nsplit);
}